// Round 5
// baseline (9798.064 us; speedup 1.0000x reference)
//
#include <hip/hip_runtime.h>
#include <hip/hip_bf16.h>

typedef __attribute__((ext_vector_type(8))) short short8;
typedef __attribute__((ext_vector_type(4))) float f32x4;

// Problem dims
#define NB 64      // batch
#define NS 1024    // seq
#define ND 512     // input dim
#define NH 512     // hidden
#define NG 2048    // 4*NH gate columns
#define M1 65536   // NB*NS rows of the input-projection GEMM

// ws layout (bytes)
#define OFF_A    0L                      // A bf16 [65536][512]           64 MB
#define OFF_XG   67108864L               // xg bf16 [1024][64][2048]     256 MB
#define OFF_WXT  335544320L              // Wxt bf16 [2048][512]           2 MB
#define OFF_WHT  337641472L              // Wht bf16 [2048][512]           2 MB
#define OFF_BC   339738624L              // bcat f32 [2048]                8 KB
#define OFF_HB   339746816L              // hb u64 [8 grp][2][8][256]    256 KB (tagged pairs)

#define OUT_HF   33554432L               // d_out offset of h_final (floats)
#define OUT_CF   33587200L               // d_out offset of c_final

static __device__ __forceinline__ ushort f2bf(float x) {
  union { float f; unsigned u; } v; v.f = x;
  unsigned r = (v.u + 0x7FFFu + ((v.u >> 16) & 1u)) >> 16;
  return (ushort)r;
}
static __device__ __forceinline__ float bf2f(ushort x) {
  union { unsigned u; float f; } v; v.u = ((unsigned)x) << 16; return v.f;
}
static __device__ __forceinline__ float sigm(float x) {
  return 1.0f / (1.0f + __expf(-x));
}
static __device__ __forceinline__ float tanh_fast(float x) {
  return 2.0f / (1.0f + __expf(-2.0f * x)) - 1.0f;
}

// ---------- phase 0a: fp32 -> bf16 convert of inputs ----------
__global__ __launch_bounds__(256) void cvt_in_k(const float* __restrict__ in,
                                                ushort* __restrict__ out) {
  long i = ((long)blockIdx.x * 256 + threadIdx.x) * 8;
  const float4* p = (const float4*)(in + i);
  float4 a = p[0], b = p[1];
  short8 o;
  o[0] = (short)f2bf(a.x); o[1] = (short)f2bf(a.y);
  o[2] = (short)f2bf(a.z); o[3] = (short)f2bf(a.w);
  o[4] = (short)f2bf(b.x); o[5] = (short)f2bf(b.y);
  o[6] = (short)f2bf(b.z); o[7] = (short)f2bf(b.w);
  *(short8*)(out + i) = o;
}

// ---------- phase 0b: transpose+convert weights, pack biases ----------
__global__ __launch_bounds__(256) void prep_w_k(
    const float* __restrict__ Wxi, const float* __restrict__ Whi, const float* __restrict__ bi,
    const float* __restrict__ Wxf, const float* __restrict__ Whf, const float* __restrict__ bff,
    const float* __restrict__ Wxo, const float* __restrict__ Who, const float* __restrict__ bo,
    const float* __restrict__ Wxc, const float* __restrict__ Whc, const float* __restrict__ bc,
    ushort* __restrict__ Wxt, ushort* __restrict__ Wht, float* __restrict__ bcat) {
  int t = blockIdx.x * 256 + threadIdx.x;   // 0 .. 2048*512-1
  int n = t >> 9, k = t & 511;
  int g = n >> 9, col = n & 511;
  const float* wx = (g == 0) ? Wxi : (g == 1) ? Wxf : (g == 2) ? Wxo : Wxc;
  const float* wh = (g == 0) ? Whi : (g == 1) ? Whf : (g == 2) ? Who : Whc;
  Wxt[t] = f2bf(wx[k * 512 + col]);
  Wht[t] = f2bf(wh[k * 512 + col]);
  if (t < 2048) {
    int g2 = t >> 9;
    const float* bp = (g2 == 0) ? bi : (g2 == 1) ? bff : (g2 == 2) ? bo : bc;
    bcat[t] = bp[t & 511];
  }
}

// ---------- phase 1: xg = A @ Wxt^T + b  (bf16 MFMA, 128x128 tiles, BK=32) ----------
__global__ __launch_bounds__(256) void gemm_x_k(const ushort* __restrict__ A,
                                                const ushort* __restrict__ Bt,
                                                const float* __restrict__ bcat,
                                                ushort* __restrict__ xg) {
  __shared__ ushort As[128 * 40];
  __shared__ ushort Bs[128 * 40];
  const int mbase = blockIdx.x * 128;
  const int nbase = blockIdx.y * 128;
  const int tid = threadIdx.x;
  const int lane = tid & 63, wave = tid >> 6;
  const int l15 = lane & 15, q = lane >> 4;
  const int wm = (wave & 1) * 64, wn = (wave >> 1) * 64;

  f32x4 acc[4][4];
#pragma unroll
  for (int j = 0; j < 4; ++j) {
    float bv = bcat[nbase + wn + j * 16 + l15];
#pragma unroll
    for (int i = 0; i < 4; ++i) acc[i][j] = (f32x4){bv, bv, bv, bv};
  }

  const int sr = tid >> 2;
  const int skk = (tid & 3) * 8;

  for (int kt = 0; kt < 16; ++kt) {
    const int kb = kt * 32;
#pragma unroll
    for (int pass = 0; pass < 2; ++pass) {
      int rr = sr + pass * 64;
      *(short8*)&As[rr * 40 + skk] = *(const short8*)&A[(long)(mbase + rr) * 512 + kb + skk];
      *(short8*)&Bs[rr * 40 + skk] = *(const short8*)&Bt[(long)(nbase + rr) * 512 + kb + skk];
    }
    __syncthreads();
    short8 af[4], bfr[4];
#pragma unroll
    for (int i = 0; i < 4; ++i)
      af[i] = *(const short8*)&As[(wm + i * 16 + l15) * 40 + q * 8];
#pragma unroll
    for (int j = 0; j < 4; ++j)
      bfr[j] = *(const short8*)&Bs[(wn + j * 16 + l15) * 40 + q * 8];
#pragma unroll
    for (int i = 0; i < 4; ++i)
#pragma unroll
      for (int j = 0; j < 4; ++j)
        acc[i][j] = __builtin_amdgcn_mfma_f32_16x16x32_bf16(af[i], bfr[j], acc[i][j], 0, 0, 0);
    __syncthreads();
  }

#pragma unroll
  for (int i = 0; i < 4; ++i) {
#pragma unroll
    for (int r = 0; r < 4; ++r) {
      int m = mbase + wm + i * 16 + q * 4 + r;
      int b = m >> 10, s = m & 1023;
      long rowoff = ((long)(s * 64 + b)) * 2048;
#pragma unroll
      for (int j = 0; j < 4; ++j) {
        int n = nbase + wn + j * 16 + l15;
        xg[rowoff + n] = f2bf(acc[i][j][r]);
      }
    }
  }
}

// ---------- phase 2: persistent recurrence, tag-in-word data-flow sync ----------
// 128 WGs = 8 groups x 16 roles. Group g = wg&7 owns batches [8g,8g+8) (M=16
// MFMA tile, rows 8..15 zero-padded); role r = wg>>3 owns h-cols [32r,32r+32).
// h exchange: WARM parity-2 buffer hb[g][t&1][8 rows][256 u64], each u64 =
// { low32: 2 packed bf16 h values, high32: step tag t }. One atomic store per
// word per step by its unique producer; readers batch 64 tagged loads and
// retry until every tag == t. Self-validating words: discovery load IS the
// data load -> no producer drain, no flag RTs, no __syncthreads anywhere.
// Race-free: tag+data share one atomic word; parity reuse is safe because a
// producer can only reach tag t+2 after all WGs completed their tag-t polls
// (its step-t+1 input required all of h_{t+1}, which required all tag-t polls).
// 256 KB total -> stays MALL-resident (fixes R4's cold-deep-buffer regression).
__global__ __launch_bounds__(256, 1) void lstm_rec_k(const ushort* __restrict__ xg,
                                                     const ushort* __restrict__ Wht,
                                                     float* __restrict__ out,
                                                     unsigned long long* hb) {
  const int wg = blockIdx.x;          // 0..127
  const int g = wg & 7, r = wg >> 3;  // group, role
  const int tid = threadIdx.x;
  const int wave = tid >> 6, lane = tid & 63;
  const int l15 = lane & 15, q = lane >> 4;

  unsigned long long* hbg = hb + (long)g * 4096;   // [2 parity][8 rows][256 u64]
  const ushort* xgg = xg + (long)g * 8 * 2048;     // group's batch-0 column

  // --- B fragments: this wave's 32 gate-cols (gates packed pairwise), pinned ---
  // B[k][n]: n(loc) = lane&15, k = kt*32 + q*8 + 0..7
  short8 bfrag[2][16];
  int gcol[2];
#pragma unroll
  for (int p = 0; p < 2; ++p) {
    int nloc = p * 16 + l15;
    gcol[p] = (nloc >> 3) * 512 + r * 32 + wave * 8 + (nloc & 7);
#pragma unroll
    for (int kt = 0; kt < 16; ++kt)
      bfrag[p][kt] = *(const short8*)&Wht[(long)gcol[p] * 512 + kt * 32 + q * 8];
  }
#pragma unroll
  for (int p = 0; p < 2; ++p)
#pragma unroll
    for (int kt = 0; kt < 16; ++kt)
      asm volatile("" : "+v"(bfrag[p][kt]));

  // prefetch xg[t=0] (h_0 == 0 implicitly: no loads, no start handshake)
  float xpre[2][4] = {{0.f, 0.f, 0.f, 0.f}, {0.f, 0.f, 0.f, 0.f}};
  if (q < 2) {
#pragma unroll
    for (int p = 0; p < 2; ++p)
#pragma unroll
      for (int rr = 0; rr < 4; ++rr)
        xpre[p][rr] = bf2f(xgg[(long)(q * 4 + rr) * 2048 + gcol[p]]);
  }

  const bool wr = (lane & 8) == 0;          // gate-dedup writer lanes
  const bool wrp = wr && ((lane & 1) == 0); // pair writer lanes
  float c4[4] = {0.f, 0.f, 0.f, 0.f};
  float hsave[4] = {0.f, 0.f, 0.f, 0.f};
  float hpsave[4] = {0.f, 0.f, 0.f, 0.f};

  for (int t = 0; t < 1024; ++t) {
    // A fragments: A[m][k], m = lane&15 (batch row; 8..15 zero pad), k = kt*32+q*8+j
    union { unsigned long long u[2]; short8 s8; } afu[16];
#pragma unroll
    for (int kt = 0; kt < 16; ++kt) { afu[kt].u[0] = 0ull; afu[kt].u[1] = 0ull; }

    if (t > 0 && l15 < 8) {
      // this lane's tagged pairs of h_t: row l15, u64 idx kt*16 + q*4 + 0..3
      const unsigned long long* hp = hbg + (t & 1) * 2048 + l15 * 256 + q * 4;
      unsigned long long v[16][4];
#pragma unroll
      for (int kt = 0; kt < 16; ++kt)
#pragma unroll
        for (int c = 0; c < 4; ++c)
          v[kt][c] = __hip_atomic_load(hp + kt * 16 + c, __ATOMIC_RELAXED,
                                       __HIP_MEMORY_SCOPE_AGENT);
      const unsigned tgt = (unsigned)t;
      for (;;) {
        unsigned bad = 0;
#pragma unroll
        for (int kt = 0; kt < 16; ++kt)
#pragma unroll
          for (int c = 0; c < 4; ++c)
            bad |= ((unsigned)(v[kt][c] >> 32)) ^ tgt;
        if (!bad) break;
#pragma unroll
        for (int kt = 0; kt < 16; ++kt)
#pragma unroll
          for (int c = 0; c < 4; ++c)
            v[kt][c] = __hip_atomic_load(hp + kt * 16 + c, __ATOMIC_RELAXED,
                                         __HIP_MEMORY_SCOPE_AGENT);
      }
      // strip tags, assemble bf16x8 fragments
#pragma unroll
      for (int kt = 0; kt < 16; ++kt) {
        afu[kt].u[0] = (v[kt][0] & 0xFFFFFFFFull) | (v[kt][1] << 32);
        afu[kt].u[1] = (v[kt][2] & 0xFFFFFFFFull) | (v[kt][3] << 32);
      }
    }

    f32x4 acc[2];
#pragma unroll
    for (int p = 0; p < 2; ++p)
#pragma unroll
      for (int rr = 0; rr < 4; ++rr)
        acc[p][rr] = xpre[p][rr];

#pragma unroll
    for (int kt = 0; kt < 16; ++kt) {
      acc[0] = __builtin_amdgcn_mfma_f32_16x16x32_bf16(afu[kt].s8, bfrag[0][kt], acc[0], 0, 0, 0);
      acc[1] = __builtin_amdgcn_mfma_f32_16x16x32_bf16(afu[kt].s8, bfrag[1][kt], acc[1], 0, 0, 0);
    }

    // elementwise: lane (bit3=0) has i (acc0), o (acc1); partner lane^8 has f, g.
    // h_{t+1} tagged stores: fire-and-forget, readers self-validate via tag.
    unsigned long long* hdst = hbg + ((t + 1) & 1) * 2048;
#pragma unroll
    for (int rr = 0; rr < 4; ++rr) {
      float a0 = acc[0][rr], a1 = acc[1][rr];
      float o0 = __shfl_xor(a0, 8);
      float o1 = __shfl_xor(a1, 8);
      float pi = wr ? a0 : o0;
      float pf = wr ? o0 : a0;
      float po = wr ? a1 : o1;
      float pg = wr ? o1 : a1;
      float ig = sigm(pi), fg = sigm(pf), og = sigm(po), gg = tanh_fast(pg);
      float cc = fg * c4[rr] + ig * gg;
      c4[rr] = cc;
      float hn = og * tanh_fast(cc);
      float hnp = __shfl_xor(hn, 1);        // partner col's h
      hsave[rr] = hn;
      hpsave[rr] = hnp;
      if (wrp && q < 2 && t < 1023) {
        unsigned pack = (unsigned)f2bf(hn) | ((unsigned)f2bf(hnp) << 16);
        unsigned long long tv = (unsigned long long)pack |
                                ((unsigned long long)(unsigned)(t + 1) << 32);
        __hip_atomic_store(&hdst[(q * 4 + rr) * 256 + r * 16 + wave * 4 + ((lane & 6) >> 1)],
                           tv, __ATOMIC_RELAXED, __HIP_MEMORY_SCOPE_AGENT);
      }
    }
    // keep h stores issued before the out/prefetch tail
    asm volatile("" ::: "memory");

    // out stores: fire-and-forget, retire during next step's poll
    if (wrp && q < 2) {
#pragma unroll
      for (int rr = 0; rr < 4; ++rr)
        *(float2*)&out[(long)(g * 8 + q * 4 + rr) * (NS * NH) + (long)t * NH +
                       r * 32 + wave * 8 + (lane & 6)] =
            make_float2(hsave[rr], hpsave[rr]);
    }

    if (t < 1023) {
      // prefetch next step's xg (read-only, cached) before next poll
      long xb2 = ((long)(t + 1) * 64) * 2048;
      if (q < 2) {
#pragma unroll
        for (int p = 0; p < 2; ++p)
#pragma unroll
          for (int rr = 0; rr < 4; ++rr)
            xpre[p][rr] = bf2f(xgg[xb2 + (long)(q * 4 + rr) * 2048 + gcol[p]]);
      }
    }
  }

  // final h / c state (t = 1023 values still in registers)
  if (wr && q < 2) {
    int hcol = r * 32 + wave * 8 + (lane & 7);
#pragma unroll
    for (int rr = 0; rr < 4; ++rr) {
      int b = g * 8 + q * 4 + rr;
      out[OUT_HF + (long)b * 512 + hcol] = hsave[rr];
      out[OUT_CF + (long)b * 512 + hcol] = c4[rr];
    }
  }
}

extern "C" void kernel_launch(void* const* d_in, const int* in_sizes, int n_in,
                              void* d_out, int out_size, void* d_ws, size_t ws_size,
                              hipStream_t stream) {
  const float* inputs = (const float*)d_in[0];
  const float* Wxi = (const float*)d_in[1];
  const float* Whi = (const float*)d_in[2];
  const float* bi  = (const float*)d_in[3];
  const float* Wxf = (const float*)d_in[4];
  const float* Whf = (const float*)d_in[5];
  const float* bff = (const float*)d_in[6];
  const float* Wxo = (const float*)d_in[7];
  const float* Who = (const float*)d_in[8];
  const float* bo  = (const float*)d_in[9];
  const float* Wxc = (const float*)d_in[10];
  const float* Whc = (const float*)d_in[11];
  const float* bc  = (const float*)d_in[12];

  char* ws = (char*)d_ws;
  ushort*  Abf  = (ushort*)(ws + OFF_A);
  ushort*  xgp  = (ushort*)(ws + OFF_XG);
  ushort*  Wxt  = (ushort*)(ws + OFF_WXT);
  ushort*  Whtp = (ushort*)(ws + OFF_WHT);
  float*   bcat = (float*)(ws + OFF_BC);
  unsigned long long* hb = (unsigned long long*)(ws + OFF_HB);

  // zero tags (tag 0 never polled: t starts at 1). 256 KB, stream-ordered.
  hipMemsetAsync(hb, 0, 262144, stream);

  cvt_in_k<<<16384, 256, 0, stream>>>(inputs, Abf);
  prep_w_k<<<4096, 256, 0, stream>>>(Wxi, Whi, bi, Wxf, Whf, bff,
                                     Wxo, Who, bo, Wxc, Whc, bc,
                                     Wxt, Whtp, bcat);
  dim3 g1(M1 / 128, NG / 128);                                      // 512 x 16
  gemm_x_k<<<g1, 256, 0, stream>>>(Abf, Wxt, bcat, xgp);
  lstm_rec_k<<<128, 256, 0, stream>>>(xgp, Whtp, (float*)d_out, hb);
}

// Round 6
// 5348.074 us; speedup vs baseline: 1.8321x; 1.8321x over previous
//
#include <hip/hip_runtime.h>
#include <hip/hip_bf16.h>

typedef __attribute__((ext_vector_type(8))) short short8;
typedef __attribute__((ext_vector_type(4))) float f32x4;

// Problem dims
#define NB 64      // batch
#define NS 1024    // seq
#define ND 512     // input dim
#define NH 512     // hidden
#define NG 2048    // 4*NH gate columns
#define M1 65536   // NB*NS rows of the input-projection GEMM

// ws layout (bytes)
#define OFF_A    0L                      // A bf16 [65536][512] 64 MB; after gemm the
                                         // region is dead and reused for hbF + ctrl
#define OFF_HBF  0L                      // hbF u32 [8 grp][2][8][256]   128 KB (XCD-L2 copy)
#define OFF_CTRL 16777216L               // fF u32[8][128] + fS u32[8][128]  8 KB
#define OFF_XG   67108864L               // xg bf16 [1024][64][2048]     256 MB
#define OFF_WXT  335544320L              // Wxt bf16 [2048][512]           2 MB
#define OFF_WHT  337641472L              // Wht bf16 [2048][512]           2 MB
#define OFF_BC   339738624L               // bcat f32 [2048]               8 KB
#define OFF_HBS  339746816L              // hbS u32 [8 grp][2][8][256]   128 KB (MALL copy)

#define OUT_HF   33554432L               // d_out offset of h_final (floats)
#define OUT_CF   33587200L               // d_out offset of c_final

static __device__ __forceinline__ ushort f2bf(float x) {
  union { float f; unsigned u; } v; v.f = x;
  unsigned r = (v.u + 0x7FFFu + ((v.u >> 16) & 1u)) >> 16;
  return (ushort)r;
}
static __device__ __forceinline__ float bf2f(ushort x) {
  union { unsigned u; float f; } v; v.u = ((unsigned)x) << 16; return v.f;
}
static __device__ __forceinline__ float sigm(float x) {
  return 1.0f / (1.0f + __expf(-x));
}
static __device__ __forceinline__ float tanh_fast(float x) {
  return 2.0f / (1.0f + __expf(-2.0f * x)) - 1.0f;
}

// sc0-only flag poll: coherent at the XCD's own L2 (~200cy) when producer is
// co-resident; may read a stale line forever when it is not -> caller bounds it.
static __device__ __forceinline__ unsigned ld_flag_sc0(const unsigned* p) {
  unsigned v;
  asm volatile("global_load_dword %0, %1, off sc0\n\ts_waitcnt vmcnt(0)"
               : "=v"(v) : "v"(p) : "memory");
  return v;
}
// sc0-only 16B data load pair (no wait; batch + one vmcnt(0) after)
static __device__ __forceinline__ void ld2_sc0(const unsigned* p,
                                               unsigned long long& a,
                                               unsigned long long& b) {
  asm volatile("global_load_dwordx2 %0, %2, off sc0\n\t"
               "global_load_dwordx2 %1, %2, off offset:8 sc0"
               : "=&v"(a), "=&v"(b) : "v"(p) : "memory");
}
// writer tail, one asm block so no compiler memop lands inside the counted
// windows. Order (vmcnt retires oldest-first, m135):
//   4x hbF sc0 ; 4x hbS sc0 sc1 ; vmcnt(4) [hbF ack'd at L2] ; fF sc0 ;
//   vmcnt(0)  [hbS ack'd at MALL + fF out] ; fS sc0 sc1.
static __device__ __forceinline__ void store_h_flags(
    unsigned* pF, unsigned* pS, unsigned d0, unsigned d1, unsigned d2, unsigned d3,
    unsigned* fFp, unsigned* fSp, unsigned tv) {
  asm volatile(
      "global_store_dword %[aF], %[d0], off sc0\n\t"
      "global_store_dword %[aF], %[d1], off offset:1024 sc0\n\t"
      "global_store_dword %[aF], %[d2], off offset:2048 sc0\n\t"
      "global_store_dword %[aF], %[d3], off offset:3072 sc0\n\t"
      "global_store_dword %[aS], %[d0], off sc0 sc1\n\t"
      "global_store_dword %[aS], %[d1], off offset:1024 sc0 sc1\n\t"
      "global_store_dword %[aS], %[d2], off offset:2048 sc0 sc1\n\t"
      "global_store_dword %[aS], %[d3], off offset:3072 sc0 sc1\n\t"
      "s_waitcnt vmcnt(4)\n\t"
      "global_store_dword %[fF], %[tv], off sc0\n\t"
      "s_waitcnt vmcnt(0)\n\t"
      "global_store_dword %[fS], %[tv], off sc0 sc1"
      :: [aF]"v"(pF), [aS]"v"(pS),
         [d0]"v"(d0), [d1]"v"(d1), [d2]"v"(d2), [d3]"v"(d3),
         [fF]"v"(fFp), [fS]"v"(fSp), [tv]"v"(tv)
      : "memory");
}

// ---------- phase 0a: fp32 -> bf16 convert of inputs ----------
__global__ __launch_bounds__(256) void cvt_in_k(const float* __restrict__ in,
                                                ushort* __restrict__ out) {
  long i = ((long)blockIdx.x * 256 + threadIdx.x) * 8;
  const float4* p = (const float4*)(in + i);
  float4 a = p[0], b = p[1];
  short8 o;
  o[0] = (short)f2bf(a.x); o[1] = (short)f2bf(a.y);
  o[2] = (short)f2bf(a.z); o[3] = (short)f2bf(a.w);
  o[4] = (short)f2bf(b.x); o[5] = (short)f2bf(b.y);
  o[6] = (short)f2bf(b.z); o[7] = (short)f2bf(b.w);
  *(short8*)(out + i) = o;
}

// ---------- phase 0b: transpose+convert weights, pack biases ----------
__global__ __launch_bounds__(256) void prep_w_k(
    const float* __restrict__ Wxi, const float* __restrict__ Whi, const float* __restrict__ bi,
    const float* __restrict__ Wxf, const float* __restrict__ Whf, const float* __restrict__ bff,
    const float* __restrict__ Wxo, const float* __restrict__ Who, const float* __restrict__ bo,
    const float* __restrict__ Wxc, const float* __restrict__ Whc, const float* __restrict__ bc,
    ushort* __restrict__ Wxt, ushort* __restrict__ Wht, float* __restrict__ bcat) {
  int t = blockIdx.x * 256 + threadIdx.x;   // 0 .. 2048*512-1
  int n = t >> 9, k = t & 511;
  int g = n >> 9, col = n & 511;
  const float* wx = (g == 0) ? Wxi : (g == 1) ? Wxf : (g == 2) ? Wxo : Wxc;
  const float* wh = (g == 0) ? Whi : (g == 1) ? Whf : (g == 2) ? Who : Whc;
  Wxt[t] = f2bf(wx[k * 512 + col]);
  Wht[t] = f2bf(wh[k * 512 + col]);
  if (t < 2048) {
    int g2 = t >> 9;
    const float* bp = (g2 == 0) ? bi : (g2 == 1) ? bff : (g2 == 2) ? bo : bc;
    bcat[t] = bp[t & 511];
  }
}

// ---------- phase 1: xg = A @ Wxt^T + b  (bf16 MFMA, 128x128 tiles, BK=32) ----------
__global__ __launch_bounds__(256) void gemm_x_k(const ushort* __restrict__ A,
                                                const ushort* __restrict__ Bt,
                                                const float* __restrict__ bcat,
                                                ushort* __restrict__ xg) {
  __shared__ ushort As[128 * 40];
  __shared__ ushort Bs[128 * 40];
  const int mbase = blockIdx.x * 128;
  const int nbase = blockIdx.y * 128;
  const int tid = threadIdx.x;
  const int lane = tid & 63, wave = tid >> 6;
  const int l15 = lane & 15, q = lane >> 4;
  const int wm = (wave & 1) * 64, wn = (wave >> 1) * 64;

  f32x4 acc[4][4];
#pragma unroll
  for (int j = 0; j < 4; ++j) {
    float bv = bcat[nbase + wn + j * 16 + l15];
#pragma unroll
    for (int i = 0; i < 4; ++i) acc[i][j] = (f32x4){bv, bv, bv, bv};
  }

  const int sr = tid >> 2;
  const int skk = (tid & 3) * 8;

  for (int kt = 0; kt < 16; ++kt) {
    const int kb = kt * 32;
#pragma unroll
    for (int pass = 0; pass < 2; ++pass) {
      int rr = sr + pass * 64;
      *(short8*)&As[rr * 40 + skk] = *(const short8*)&A[(long)(mbase + rr) * 512 + kb + skk];
      *(short8*)&Bs[rr * 40 + skk] = *(const short8*)&Bt[(long)(nbase + rr) * 512 + kb + skk];
    }
    __syncthreads();
    short8 af[4], bfr[4];
#pragma unroll
    for (int i = 0; i < 4; ++i)
      af[i] = *(const short8*)&As[(wm + i * 16 + l15) * 40 + q * 8];
#pragma unroll
    for (int j = 0; j < 4; ++j)
      bfr[j] = *(const short8*)&Bs[(wn + j * 16 + l15) * 40 + q * 8];
#pragma unroll
    for (int i = 0; i < 4; ++i)
#pragma unroll
      for (int j = 0; j < 4; ++j)
        acc[i][j] = __builtin_amdgcn_mfma_f32_16x16x32_bf16(af[i], bfr[j], acc[i][j], 0, 0, 0);
    __syncthreads();
  }

#pragma unroll
  for (int i = 0; i < 4; ++i) {
#pragma unroll
    for (int r = 0; r < 4; ++r) {
      int m = mbase + wm + i * 16 + q * 4 + r;
      int b = m >> 10, s = m & 1023;
      long rowoff = ((long)(s * 64 + b)) * 2048;
#pragma unroll
      for (int j = 0; j < 4; ++j) {
        int n = nbase + wn + j * 16 + l15;
        xg[rowoff + n] = f2bf(acc[i][j][r]);
      }
    }
  }
}

// ---------- phase 2: persistent recurrence, dual-scope (XCD-L2 + MALL) sync ----------
// 128 WGs = 8 groups x 16 roles; group g = wg&7 owns batches [8g,8g+8) (M=16 tile,
// rows 8..15 zero-padded); role r = wg>>3 owns h-cols [32r,32r+32); wave w owns 8.
// Writers publish h + per-wave flag TWICE: sc0 copy (coherent at the XCD's shared
// L2 iff consumer co-resident — expected under round-robin dispatch, g == XCD id)
// and sc0 sc1 copy (MALL, guaranteed). Counted vmcnt orders each copy's flag after
// its h stores. Readers: bounded sc0 flag spin (64 polls) -> fallback to the PROVEN
// MALL flag spin + MALL data (exact R3 semantics); ballot makes the per-wave data
// source uniform; hysteresis pins a wave to the slow path after one failure.
// Hang-impossible: the MALL path alone is complete; no barriers, no detection.
// Parity-2 reuse safe: producer reaches step u+1 only after all flags >= u+1,
// which implies every reader finished its parity-(u&1) reads (R3 argument).
__global__ __launch_bounds__(256, 1) void lstm_rec_k(const ushort* __restrict__ xg,
                                                     const ushort* __restrict__ Wht,
                                                     float* __restrict__ out,
                                                     unsigned* hbF, unsigned* hbS,
                                                     unsigned* ctrl) {
  const int wg = blockIdx.x;          // 0..127
  const int g = wg & 7, r = wg >> 3;  // group (expected XCD id), role
  const int tid = threadIdx.x;
  const int wave = tid >> 6, lane = tid & 63;
  const int l15 = lane & 15, q = lane >> 4;

  unsigned* hbFg = hbF + g * 4096;    // [2 parity][8 rows][256 u32]
  unsigned* hbSg = hbS + g * 4096;
  unsigned* fF = ctrl + g * 128;      // 64 per-wave flags (idx = role*4 + wave)
  unsigned* fS = ctrl + 1024 + g * 128;
  const ushort* xgg = xg + (long)g * 8 * 2048;  // group's batch-0 column

  // --- B fragments: this wave's 32 gate-cols (gates packed pairwise), pinned ---
  short8 bfrag[2][16];
  int gcol[2];
#pragma unroll
  for (int p = 0; p < 2; ++p) {
    int nloc = p * 16 + l15;
    gcol[p] = (nloc >> 3) * 512 + r * 32 + wave * 8 + (nloc & 7);
#pragma unroll
    for (int kt = 0; kt < 16; ++kt)
      bfrag[p][kt] = *(const short8*)&Wht[(long)gcol[p] * 512 + kt * 32 + q * 8];
  }
#pragma unroll
  for (int p = 0; p < 2; ++p)
#pragma unroll
    for (int kt = 0; kt < 16; ++kt)
      asm volatile("" : "+v"(bfrag[p][kt]));

  // prefetch xg[t=0] (h_0 == 0 implicit: no loads, no start handshake)
  float xpre[2][4] = {{0.f, 0.f, 0.f, 0.f}, {0.f, 0.f, 0.f, 0.f}};
  if (q < 2) {
#pragma unroll
    for (int p = 0; p < 2; ++p)
#pragma unroll
      for (int rr = 0; rr < 4; ++rr)
        xpre[p][rr] = bf2f(xgg[(long)(q * 4 + rr) * 2048 + gcol[p]]);
  }

  const bool wr = (lane & 8) == 0;          // gate-dedup writer lanes
  const bool wrp = wr && ((lane & 1) == 0); // pair writer lanes
  float c4[4] = {0.f, 0.f, 0.f, 0.f};
  float hsave[4] = {0.f, 0.f, 0.f, 0.f};
  float hpsave[4] = {0.f, 0.f, 0.f, 0.f};
  bool tryfast = true;                      // hysteresis: drop to slow-only forever on failure
  const unsigned* fFl = fF + lane;          // lane l waits producer wave (role l>>2, wave l&3)
  const unsigned* fSl = fS + lane;

  for (int t = 0; t < 1024; ++t) {
    union { unsigned long long u[2]; short8 s8; } afu[16];
#pragma unroll
    for (int kt = 0; kt < 16; ++kt) { afu[kt].u[0] = 0ull; afu[kt].u[1] = 0ull; }

    if (t > 0) {
      // ---- flag wait: bounded fast (XCD-L2) spin, guaranteed MALL fallback ----
      bool myfast = false;
      if (tryfast) {
        myfast = true;
        int spins = 0;
        while (ld_flag_sc0(fFl) < (unsigned)t) {
          if (++spins >= 64) { myfast = false; break; }
        }
      }
      if (!myfast) {
        while (__hip_atomic_load(fSl, __ATOMIC_RELAXED, __HIP_MEMORY_SCOPE_AGENT) <
               (unsigned)t) {}
      }
      unsigned long long bal = __ballot(myfast ? 1 : 0);
      const bool all_fast = (bal == 0xFFFFFFFFFFFFFFFFull);
      tryfast = tryfast && all_fast;
      asm volatile("" ::: "memory");        // no data-load hoisting above the wait

      // ---- data loads, wave-uniform source ----
      if (all_fast) {
        if (l15 < 8) {
          const unsigned* baseF = hbFg + (t & 1) * 2048 + l15 * 256 + q * 4;
#pragma unroll
          for (int kt = 0; kt < 16; ++kt)
            ld2_sc0(baseF + kt * 16, afu[kt].u[0], afu[kt].u[1]);
        }
        asm volatile("s_waitcnt vmcnt(0)" ::: "memory");
        __builtin_amdgcn_sched_barrier(0);  // rule 18: keep MFMA after the wait
      } else {
        if (l15 < 8) {
          const unsigned* base = hbSg + (t & 1) * 2048 + l15 * 256 + q * 4;
#pragma unroll
          for (int kt = 0; kt < 16; ++kt) {
            const unsigned long long* p = (const unsigned long long*)(base + kt * 16);
            afu[kt].u[0] = __hip_atomic_load(p, __ATOMIC_RELAXED, __HIP_MEMORY_SCOPE_AGENT);
            afu[kt].u[1] = __hip_atomic_load(p + 1, __ATOMIC_RELAXED, __HIP_MEMORY_SCOPE_AGENT);
          }
        }
      }
    }

    f32x4 acc[2];
#pragma unroll
    for (int p = 0; p < 2; ++p)
#pragma unroll
      for (int rr = 0; rr < 4; ++rr)
        acc[p][rr] = xpre[p][rr];

#pragma unroll
    for (int kt = 0; kt < 16; ++kt) {
      acc[0] = __builtin_amdgcn_mfma_f32_16x16x32_bf16(afu[kt].s8, bfrag[0][kt], acc[0], 0, 0, 0);
      acc[1] = __builtin_amdgcn_mfma_f32_16x16x32_bf16(afu[kt].s8, bfrag[1][kt], acc[1], 0, 0, 0);
    }

    // elementwise: lane (bit3=0) has i (acc0), o (acc1); partner lane^8 has f, g.
    unsigned packs[4];
#pragma unroll
    for (int rr = 0; rr < 4; ++rr) {
      float a0 = acc[0][rr], a1 = acc[1][rr];
      float o0 = __shfl_xor(a0, 8);
      float o1 = __shfl_xor(a1, 8);
      float pi = wr ? a0 : o0;
      float pf = wr ? o0 : a0;
      float po = wr ? a1 : o1;
      float pg = wr ? o1 : a1;
      float ig = sigm(pi), fg = sigm(pf), og = sigm(po), gg = tanh_fast(pg);
      float cc = fg * c4[rr] + ig * gg;
      c4[rr] = cc;
      float hn = og * tanh_fast(cc);
      float hnp = __shfl_xor(hn, 1);        // partner col's h
      hsave[rr] = hn;
      hpsave[rr] = hnp;
      packs[rr] = (unsigned)f2bf(hn) | ((unsigned)f2bf(hnp) << 16);
    }

    // ---- dual publish (8 writer lanes per wave; per-wave flags) ----
    if (t < 1023 && wrp && q < 2) {
      const int loff = q * 1024 + r * 16 + wave * 4 + ((lane & 6) >> 1);
      unsigned* pF = hbFg + ((t + 1) & 1) * 2048 + loff;
      unsigned* pS = hbSg + ((t + 1) & 1) * 2048 + loff;
      store_h_flags(pF, pS, packs[0], packs[1], packs[2], packs[3],
                    fF + r * 4 + wave, fS + r * 4 + wave, (unsigned)(t + 1));
    }

    // out stores: fire-and-forget, retire during next step's wait
    if (wrp && q < 2) {
#pragma unroll
      for (int rr = 0; rr < 4; ++rr)
        *(float2*)&out[(long)(g * 8 + q * 4 + rr) * (NS * NH) + (long)t * NH +
                       r * 32 + wave * 8 + (lane & 6)] =
            make_float2(hsave[rr], hpsave[rr]);
    }

    if (t < 1023) {
      // prefetch next step's xg (read-only, cached) before next wait
      long xb2 = ((long)(t + 1) * 64) * 2048;
      if (q < 2) {
#pragma unroll
        for (int p = 0; p < 2; ++p)
#pragma unroll
          for (int rr = 0; rr < 4; ++rr)
            xpre[p][rr] = bf2f(xgg[xb2 + (long)(q * 4 + rr) * 2048 + gcol[p]]);
      }
    }
  }

  // final h / c state (t = 1023 values still in registers)
  if (wr && q < 2) {
    int hcol = r * 32 + wave * 8 + (lane & 7);
#pragma unroll
    for (int rr = 0; rr < 4; ++rr) {
      int b = g * 8 + q * 4 + rr;
      out[OUT_HF + (long)b * 512 + hcol] = hsave[rr];
      out[OUT_CF + (long)b * 512 + hcol] = c4[rr];
    }
  }
}

extern "C" void kernel_launch(void* const* d_in, const int* in_sizes, int n_in,
                              void* d_out, int out_size, void* d_ws, size_t ws_size,
                              hipStream_t stream) {
  const float* inputs = (const float*)d_in[0];
  const float* Wxi = (const float*)d_in[1];
  const float* Whi = (const float*)d_in[2];
  const float* bi  = (const float*)d_in[3];
  const float* Wxf = (const float*)d_in[4];
  const float* Whf = (const float*)d_in[5];
  const float* bff = (const float*)d_in[6];
  const float* Wxo = (const float*)d_in[7];
  const float* Who = (const float*)d_in[8];
  const float* bo  = (const float*)d_in[9];
  const float* Wxc = (const float*)d_in[10];
  const float* Whc = (const float*)d_in[11];
  const float* bc  = (const float*)d_in[12];

  char* ws = (char*)d_ws;
  ushort*  Abf  = (ushort*)(ws + OFF_A);
  ushort*  xgp  = (ushort*)(ws + OFF_XG);
  ushort*  Wxt  = (ushort*)(ws + OFF_WXT);
  ushort*  Whtp = (ushort*)(ws + OFF_WHT);
  float*   bcat = (float*)(ws + OFF_BC);
  unsigned* hbF = (unsigned*)(ws + OFF_HBF);   // in dead A region
  unsigned* hbS = (unsigned*)(ws + OFF_HBS);
  unsigned* ctrl = (unsigned*)(ws + OFF_CTRL); // in dead A region

  cvt_in_k<<<16384, 256, 0, stream>>>(inputs, Abf);
  prep_w_k<<<4096, 256, 0, stream>>>(Wxi, Whi, bi, Wxf, Whf, bff,
                                     Wxo, Who, bo, Wxc, Whc, bc,
                                     Wxt, Whtp, bcat);
  dim3 g1(M1 / 128, NG / 128);                                      // 512 x 16
  gemm_x_k<<<g1, 256, 0, stream>>>(Abf, Wxt, bcat, xgp);
  // A region is dead after gemm_x_k: zero both flag arrays (stream-ordered).
  // h buffers need no init (flag-gated before first read).
  hipMemsetAsync(ctrl, 0, 8192, stream);
  lstm_rec_k<<<128, 256, 0, stream>>>(xgp, Whtp, (float*)d_out, hbF, hbS, ctrl);
}